// Round 8
// baseline (50.401 us; speedup 1.0000x reference)
//
#include <hip/hip_runtime.h>
#include <math.h>

#define CI 64
#define CO 128
#define CX 69
#define LPIX 1024   // 32*32

typedef __attribute__((ext_vector_type(8))) short bf16x8;
typedef __attribute__((ext_vector_type(4))) float f32x4;

// ws byte offsets
#define WMF_OFF  0                        // u16[9*128*64] = 147456 B
#define SKT_OFF  147456                   // f32[45*128]   = 23040 B
#define QP_OFF   (147456 + 23040)         // f32[2*16*1024]= 131072 B
#define CNT_OFF  (QP_OFF + 131072)        // int[256]      = 1024 B

__device__ __forceinline__ unsigned short f2bf(float f) {
  unsigned u = __float_as_uint(f);
  unsigned r = (u + 0x7fffu + ((u >> 16) & 1u)) >> 16;
  return (unsigned short)r;
}

// ---------------------------------------------------------------------------
// prepW: weights -> wmf[tap][co][ci ^ ((co&7)<<3)] bf16 (pre-swizzled so the
// LDS A-image is linear + frag ds_read_b128 conflict-free);
// shapes_kernel -> skt[j][co] f32; zero the 256 dependency counters.
// ---------------------------------------------------------------------------
__launch_bounds__(256)
__global__ void prepW(const float* __restrict__ cwg,
                      const float* __restrict__ skg,
                      unsigned short* __restrict__ wmf,
                      float* __restrict__ skt,
                      int* __restrict__ cnt) {
  int i = blockIdx.x * 256 + threadIdx.x;
  if (i < 9 * 128 * 64) {
    int tap = i >> 13;
    int rem = i & 8191;
    int co = rem >> 6, cis = rem & 63;
    int ci = cis ^ ((co & 7) << 3);
    wmf[i] = f2bf(cwg[co * 576 + ci * 9 + tap]);
  } else {
    int d = i - 9 * 128 * 64;
    if (d < 45 * 128) {
      int j = d >> 7, co = d & 127;
      skt[j * 128 + co] = skg[co * 45 + j];
    } else {
      int c = d - 45 * 128;
      if (c < 256) cnt[c] = 0;
    }
  }
}

// ---------------------------------------------------------------------------
// convFused: conv3x3 (zero-pad) via bf16 MFMA 16x16x32 + fused epilogue
// (bias, L1 shape-distance, saf, q partial) + fused window-stats via
// device-scope dependency counters (stats job for a row-pair runs on the
// block that completes its 6 (interior) / 4 (edge) contributor count).
// grid 512 = 16 b x 16 row-pairs x 2 co-halves; 256 thr = 4 waves.
// ---------------------------------------------------------------------------
__launch_bounds__(256, 3)
__global__ void convFused(const float* __restrict__ xg,
                          const unsigned short* __restrict__ wmf,
                          const float* __restrict__ cbg,
                          const float* __restrict__ w2g,
                          const float* __restrict__ b2g,
                          const float* __restrict__ sktg,
                          float* __restrict__ qp,
                          int* __restrict__ cnt,
                          float* __restrict__ outg) {
  __shared__ char arena[16384];              // A dbuf (2x8KB) -> lds_c (16KB)
  __shared__ unsigned short ldsB[4 * 36 * 64]; // 18432 B
  __shared__ float lds_sx[5 * 144];          // shape rows, edge-clamped
  __shared__ float qred[4][64];
  __shared__ int jobs[3];

  unsigned short* A0 = (unsigned short*)arena;
  float* lds_c = (float*)arena;

  const int tid = threadIdx.x;
  const int blk = blockIdx.x;
  const int coh = blk & 1;
  const int rp  = (blk >> 1) & 15;
  const int b   = blk >> 5;
  const int r0  = rp * 2;

  const int w    = tid >> 6;
  const int lane = tid & 63;
  const int rsel = w >> 1;          // MFMA-phase: wave's row within pair
  const int cq   = w & 1;           // MFMA-phase: co quarter within half
  const int n16  = lane & 15;
  const int kq   = lane >> 4;

  const float* xb = xg + (size_t)b * CX * LPIX;
  const float* xs = xb + CI * LPIX;

  // ---- stage B: x rows r0-1..r0+2, col slot s holds global col s-1, bf16,
  // ci-group XOR-swizzled by (slot&7). Zero rows/cols OOB.
  {
    const int col = tid & 31;          // global col = lane32
    const int grp = tid >> 5;          // 8 groups
    const int slot = col + 1;
    const int swk = (slot & 7) << 3;
    #pragma unroll
    for (int it = 0; it < 16; ++it) {
      const int rc  = grp + it * 8;    // 0..127 = row(2b) x cipair(5b)
      const int row = rc >> 5;
      const int ci  = (rc & 31) * 2;
      const int grow = r0 - 1 + row;
      unsigned v = 0;
      if ((unsigned)grow < 32u) {
        float f0 = xb[ci * LPIX + grow * 32 + col];
        float f1 = xb[(ci + 1) * LPIX + grow * 32 + col];
        v = (unsigned)f2bf(f0) | ((unsigned)f2bf(f1) << 16);
      }
      const int gslot = ((ci >> 3) << 3) ^ swk;
      ((unsigned*)ldsB)[(((row * 36 + slot) << 6) + gslot + (ci & 7)) >> 1] = v;
    }
    // zero pad slots 0,33,34,35 (4 rows x 32 ci-pairs each)
    for (int idx = tid; idx < 512; idx += 256) {
      const int row = idx >> 7;
      const int s4  = (idx >> 5) & 3;
      const int sl  = (s4 == 0) ? 0 : (32 + s4);
      const int ci  = (idx & 31) * 2;
      const int gsl = ((ci >> 3) << 3) ^ ((sl & 7) << 3);
      ((unsigned*)ldsB)[(((row * 36 + sl) << 6) + gsl + (ci & 7)) >> 1] = 0;
    }
  }

  // ---- stage shape rows (edge clamp) for the epilogue
  for (int idx = tid; idx < 5 * 144; idx += 256) {
    int c = idx / 144, rem = idx - c * 144;
    int s = rem / 36, j = rem - s * 36;
    int hh = r0 - 1 + s; hh = hh < 0 ? 0 : (hh > 31 ? 31 : hh);
    int col = j - 1;     col = col < 0 ? 0 : (col > 31 ? 31 : col);
    lds_sx[idx] = xs[c * LPIX + hh * 32 + col];
  }

  // ---- stage tap 0 A-tile (this co half: 64 co x 64 ci bf16 = 8 KB)
  {
    const uint4* s = (const uint4*)(wmf + (size_t)(coh * 64) * 64);
    uint4 v0 = s[tid], v1 = s[tid + 256];
    uint4* d = (uint4*)A0;
    d[tid] = v0; d[tid + 256] = v1;
  }
  __syncthreads();

  f32x4 acc[2][2] = {};

  for (int tap = 0; tap < 9; ++tap) {
    const int dr = tap / 3, dc = tap % 3;
    uint4 pf0, pf1;
    if (tap < 8) {
      const uint4* s = (const uint4*)(wmf + (size_t)((tap + 1) * 128 + coh * 64) * 64);
      pf0 = s[tid]; pf1 = s[tid + 256];
    }
    const int rowst = rsel + dr;                 // staged row 0..3
    const unsigned short* abase = A0 + (tap & 1) * 4096;
    #pragma unroll
    for (int ci0 = 0; ci0 < 64; ci0 += 32) {
      const int g = (ci0 >> 3) + kq;             // ci group 0..7
      bf16x8 bfr[2];
      #pragma unroll
      for (int t = 0; t < 2; ++t) {
        const int slot = t * 16 + n16 + dc;      // 0..33
        const int gs = (g ^ (slot & 7)) << 3;
        bfr[t] = *(const bf16x8*)(ldsB + ((rowst * 36 + slot) << 6) + gs);
      }
      const int gsa = ((kq | (ci0 >> 3)) ^ (n16 & 7)) << 3;
      #pragma unroll
      for (int ct = 0; ct < 2; ++ct) {
        const int co_l = cq * 32 + ct * 16 + n16;
        bf16x8 a = *(const bf16x8*)(abase + co_l * 64 + gsa);
        acc[0][ct] = __builtin_amdgcn_mfma_f32_16x16x32_bf16(a, bfr[0], acc[0][ct], 0, 0, 0);
        acc[1][ct] = __builtin_amdgcn_mfma_f32_16x16x32_bf16(a, bfr[1], acc[1][ct], 0, 0, 0);
      }
    }
    if (tap < 8) {
      uint4* d = (uint4*)(A0 + ((tap + 1) & 1) * 4096);
      d[tid] = pf0; d[tid + 256] = pf1;
    }
    __syncthreads();   // also separates last A-reads from lds_c writes below
  }

  // ---- transpose acc through LDS: [px 0..63][co_l 0..63], XOR-swizzled f32x4
  // C layout (validated r5/r6): col(px in tile)=n16, row(co in tile)=kq*4+reg
  #pragma unroll
  for (int pt = 0; pt < 2; ++pt) {
    const int pxl = rsel * 32 + pt * 16 + n16;
    #pragma unroll
    for (int ct = 0; ct < 2; ++ct) {
      const int cog = cq * 8 + ct * 4 + kq;       // co_l/4 group: 0..15
      const int sg  = cog ^ (pxl & 7);
      *(f32x4*)&lds_c[pxl * 64 + sg * 4] = acc[pt][ct];
    }
  }
  __syncthreads();

  // ---- epilogue: wave wS -> co chunk [wS*16, wS*16+16) of this half; lane = px
  const int wS   = __builtin_amdgcn_readfirstlane(w);
  const int co0g = coh * 64 + wS * 16;
  const int pxl  = lane;

  float cvals[16];
  #pragma unroll
  for (int g = 0; g < 4; ++g) {
    const int cog = wS * 4 + g;
    const int sg  = cog ^ (pxl & 7);
    *(f32x4*)&cvals[g * 4] = *(const f32x4*)&lds_c[pxl * 64 + sg * 4];
  }

  // shape windows into registers (center-relative for channels 0,1)
  const int xbase = (pxl >> 5) * 36 + (pxl & 31);
  float swv[45];
  {
    const float c0 = lds_sx[0 * 144 + 37 + xbase];
    const float c1 = lds_sx[1 * 144 + 37 + xbase];
    #pragma unroll
    for (int c = 0; c < 5; ++c) {
      float ctr = (c == 0) ? c0 : ((c == 1) ? c1 : 0.f);
      #pragma unroll
      for (int s = 0; s < 3; ++s)
        #pragma unroll
        for (int dc = 0; dc < 3; ++dc)
          swv[c * 9 + s * 3 + dc] = lds_sx[c * 144 + s * 36 + dc + xbase] - ctr;
    }
  }

  // sd via wave-uniform scalar loads + pure VALU
  float sd[16];
  #pragma unroll
  for (int k = 0; k < 16; ++k) sd[k] = 0.f;
  const float* skt = sktg + co0g;
  #pragma unroll
  for (int j = 0; j < 45; ++j) {
    const float sv = swv[j];
    #pragma unroll
    for (int k = 0; k < 16; ++k)
      sd[k] += fabsf(sv - skt[j * 128 + k]);
  }

  // bias + saf = relu(conv/(sd+1)) + store + q partial
  float qpv = 0.f;
  float* ob = outg + ((size_t)b * 133 + co0g) * LPIX + (r0 + (pxl >> 5)) * 32 + (pxl & 31);
  #pragma unroll
  for (int k = 0; k < 16; ++k) {
    float v = (cvals[k] + cbg[co0g + k]) * __builtin_amdgcn_rcpf(sd[k] + 1.0f);
    v = v > 0.f ? v : 0.f;
    ob[(size_t)k * LPIX] = v;
    qpv = fmaf(v, w2g[co0g + k], qpv);
  }

  // in-block q reduction over the 4 waves (this half's 64 co)
  qred[w][lane] = qpv;
  __syncthreads();
  if (tid < 64) {
    float q = qred[0][tid] + qred[1][tid] + qred[2][tid] + qred[3][tid];
    qp[coh * 16384 + b * LPIX + r0 * 32 + tid] = q;
  }
  __syncthreads();

  // ---- dependency counters: claim stats jobs whose inputs are complete.
  // Counter (b,r) targets: 6 interior (row-pairs r-1,r,r+1 x 2 halves),
  // 4 at r=0 or r=15.
  if (tid == 0) {
    __threadfence();                       // release our qp writes (agent)
    jobs[0] = jobs[1] = jobs[2] = -1;
    int n = 0;
    const int lo = (rp == 0) ? 0 : rp - 1;
    const int hi = (rp == 15) ? 15 : rp + 1;
    for (int r = lo; r <= hi; ++r) {
      const int tgt = (r == 0 || r == 15) ? 4 : 6;
      int old = atomicAdd(&cnt[b * 16 + r], 1);
      if (old == tgt - 1) jobs[n++] = r;
    }
    __threadfence();                       // acquire other blocks' qp writes
  }
  __syncthreads();

  const int job = (w < 3) ? jobs[w] : -1;
  if (job >= 0) {
    // stats for (b, job): lane = pixel of the 2-row stripe
    const int h   = job * 2 + (lane >> 5);
    const int wcx = lane & 31;
    const float b2 = b2g[0];
    const float* qb0 = qp + (size_t)b * LPIX;
    const float* qb1 = qb0 + 16384;

    float qv[9];
    float mm = -1e30f;
    #pragma unroll
    for (int t = 0; t < 9; ++t) {
      int hh = h + t / 3 - 1, wc2 = wcx + t % 3 - 1;
      float v = 0.f;  // zero padding participates in softmax
      if ((unsigned)hh < 32u && (unsigned)wc2 < 32u) {
        int off = hh * 32 + wc2;
        v = (qb0[off] + qb1[off] + b2) * 0.08838834764831845f;  // 1/sqrt(128)
      }
      qv[t] = v;
      mm = fmaxf(mm, v);
    }
    float ssum = 0.f;
    #pragma unroll
    for (int t = 0; t < 9; ++t) { qv[t] = expf(qv[t] - mm); ssum += qv[t]; }
    const float inv = 1.f / ssum;

    float um0[9], um1[9];
    float m0 = 0.f, m1 = 0.f, v1a = 0.f, v1b = 0.f, c1 = 0.f;
    #pragma unroll
    for (int t = 0; t < 9; ++t) {
      int hh = h + t / 3 - 1; hh = hh < 0 ? 0 : (hh > 31 ? 31 : hh);  // edge pad
      int wc2 = wcx + t % 3 - 1; wc2 = wc2 < 0 ? 0 : (wc2 > 31 ? 31 : wc2);
      int off = hh * 32 + wc2;
      float quv = qv[t] * inv;
      qv[t] = quv;
      float a0 = xs[off];
      float a1 = xs[LPIX + off];
      float b0 = xs[2 * LPIX + off];
      float b1 = xs[3 * LPIX + off];
      float cc = xs[4 * LPIX + off];
      um0[t] = a0; um1[t] = a1;
      m0 = fmaf(a0, quv, m0);
      m1 = fmaf(a1, quv, m1);
      v1a = fmaf(b0, quv, v1a);
      v1b = fmaf(b1, quv, v1b);
      c1 = fmaf(cc, quv, c1);
    }
    float var0 = v1a, var1 = v1b, cov = c1;
    #pragma unroll
    for (int t = 0; t < 9; ++t) {
      float d0 = um0[t] - m0, d1 = um1[t] - m1;
      var0 = fmaf(d0 * d0, qv[t], var0);
      var1 = fmaf(d1 * d1, qv[t], var1);
      cov  = fmaf(d0 * d1, qv[t], cov);
    }
    float* ob2 = outg + ((size_t)b * 133 + 128) * LPIX + h * 32 + wcx;
    ob2[0 * LPIX] = m0;
    ob2[1 * LPIX] = m1;
    ob2[2 * LPIX] = var0;
    ob2[3 * LPIX] = var1;
    ob2[4 * LPIX] = cov;
  }
}

extern "C" void kernel_launch(void* const* d_in, const int* in_sizes, int n_in,
                              void* d_out, int out_size, void* d_ws, size_t ws_size,
                              hipStream_t stream) {
  const float* x  = (const float*)d_in[0];
  const float* cw = (const float*)d_in[1];
  const float* cb = (const float*)d_in[2];
  const float* w2 = (const float*)d_in[3];
  const float* b2 = (const float*)d_in[4];
  const float* sk = (const float*)d_in[5];
  float* out = (float*)d_out;

  unsigned short* wmf = (unsigned short*)((char*)d_ws + WMF_OFF);
  float* skt = (float*)((char*)d_ws + SKT_OFF);
  float* qp  = (float*)((char*)d_ws + QP_OFF);
  int*   cnt = (int*)((char*)d_ws + CNT_OFF);

  prepW<<<dim3(312), dim3(256), 0, stream>>>(cw, sk, wmf, skt, cnt);
  convFused<<<dim3(512), dim3(256), 0, stream>>>(x, wmf, cb, w2, b2, skt, qp, cnt, out);
}

// Round 9
// 36.950 us; speedup vs baseline: 1.3640x; 1.3640x over previous
//
#include <hip/hip_runtime.h>
#include <math.h>

#define CI 64
#define CO 128
#define CX 69
#define LPIX 1024   // 32*32

typedef __attribute__((ext_vector_type(8))) short bf16x8;
typedef __attribute__((ext_vector_type(4))) float f32x4;

// ws byte offsets
#define WMF_OFF  0                        // u16[128*9*64] = 147456 B
#define SKT_OFF  147456                   // f32[45*128]   = 23040 B
#define QP_OFF   (147456 + 23040)         // f32[2*16*1024]= 131072 B

__device__ __forceinline__ unsigned short f2bf(float f) {
  unsigned u = __float_as_uint(f);
  unsigned r = (u + 0x7fffu + ((u >> 16) & 1u)) >> 16;
  return (unsigned short)r;
}

// ---------------------------------------------------------------------------
// prepW: weights -> wmf[co][tap][ci] bf16 (so a lane's A-fragment for all 9
// taps is one base pointer + tap*128B immediate offsets, straight from L2);
// shapes_kernel -> skt[j][co] f32.
// ---------------------------------------------------------------------------
__launch_bounds__(256)
__global__ void prepW(const float* __restrict__ cwg,
                      const float* __restrict__ skg,
                      unsigned short* __restrict__ wmf,
                      float* __restrict__ skt) {
  int i = blockIdx.x * 256 + threadIdx.x;
  if (i < 128 * 9 * 64) {
    int co = i / 576, rem = i - co * 576;
    int tap = rem >> 6, ci = rem & 63;
    wmf[i] = f2bf(cwg[co * 576 + ci * 9 + tap]);
  } else {
    int d = i - 128 * 9 * 64;
    if (d < 45 * 128) {
      int j = d >> 7, co = d & 127;
      skt[j * 128 + co] = skg[co * 45 + j];
    }
  }
}

// ---------------------------------------------------------------------------
// convFused: conv3x3 (zero-pad) via bf16 MFMA 16x16x32 + fused epilogue
// (bias, L1 shape-distance, saf, q partial).
// grid 512 = 16 b x 16 row-pairs x 2 co-halves; 256 thr = 4 waves.
// B (x window) staged in LDS: [4 rows][36 col-slots][64 ci^swz] bf16,
// zero-padded rows/cols -> uniform tap loop. A fragments read DIRECTLY from
// global (L2-resident 147 KB): no A staging, no in-loop barriers -- vmcnt
// (A) and lgkmcnt (B) overlap freely across 8 waves/CU.
// Epilogue: acc transposed through LDS (aliases dead B buffer), wave = 16-co
// chunk, lane = pixel: sd via wave-uniform s_loads + pure VALU.
// ---------------------------------------------------------------------------
__launch_bounds__(256, 2)
__global__ void convFused(const float* __restrict__ xg,
                          const unsigned short* __restrict__ wmfg,
                          const float* __restrict__ cbg,
                          const float* __restrict__ w2g,
                          const float* __restrict__ sktg,
                          float* __restrict__ qp,
                          float* __restrict__ outg) {
  __shared__ char arena[18432];       // ldsB (18432 B) -> lds_c (16384 B)
  __shared__ float lds_sx[5 * 144];   // shape rows, edge-clamped
  __shared__ float qred[4][64];

  unsigned short* ldsB = (unsigned short*)arena;
  float* lds_c = (float*)arena;

  const int tid = threadIdx.x;
  const int blk = blockIdx.x;
  const int coh = blk & 1;
  const int rp  = (blk >> 1) & 15;
  const int b   = blk >> 5;
  const int r0  = rp * 2;

  const int w    = tid >> 6;
  const int lane = tid & 63;
  const int rsel = w >> 1;          // MFMA-phase: wave's row within pair
  const int cq   = w & 1;           // MFMA-phase: co quarter within half
  const int n16  = lane & 15;
  const int kq   = lane >> 4;

  const float* xb = xg + (size_t)b * CX * LPIX;
  const float* xs = xb + CI * LPIX;

  // ---- stage B: x rows r0-1..r0+2, col slot s holds global col s-1, bf16,
  // ci-group XOR-swizzled by (slot&7). Zero rows/cols OOB.
  {
    const int col = tid & 31;          // global col = lane32
    const int grp = tid >> 5;          // 8 groups
    const int slot = col + 1;
    const int swk = (slot & 7) << 3;
    #pragma unroll
    for (int it = 0; it < 16; ++it) {
      const int rc  = grp + it * 8;    // 0..127 = row(2b) x cipair(5b)
      const int row = rc >> 5;
      const int ci  = (rc & 31) * 2;
      const int grow = r0 - 1 + row;
      unsigned v = 0;
      if ((unsigned)grow < 32u) {
        float f0 = xb[ci * LPIX + grow * 32 + col];
        float f1 = xb[(ci + 1) * LPIX + grow * 32 + col];
        v = (unsigned)f2bf(f0) | ((unsigned)f2bf(f1) << 16);
      }
      const int gslot = ((ci >> 3) << 3) ^ swk;
      ((unsigned*)ldsB)[(((row * 36 + slot) << 6) + gslot + (ci & 7)) >> 1] = v;
    }
    // zero pad slots 0,33,34,35 (4 rows x 32 ci-pairs each)
    for (int idx = tid; idx < 512; idx += 256) {
      const int row = idx >> 7;
      const int s4  = (idx >> 5) & 3;
      const int sl  = (s4 == 0) ? 0 : (32 + s4);
      const int ci  = (idx & 31) * 2;
      const int gsl = ((ci >> 3) << 3) ^ ((sl & 7) << 3);
      ((unsigned*)ldsB)[(((row * 36 + sl) << 6) + gsl + (ci & 7)) >> 1] = 0;
    }
  }

  // ---- stage shape rows (edge clamp) for the epilogue
  for (int idx = tid; idx < 5 * 144; idx += 256) {
    int c = idx / 144, rem = idx - c * 144;
    int s = rem / 36, j = rem - s * 36;
    int hh = r0 - 1 + s; hh = hh < 0 ? 0 : (hh > 31 ? 31 : hh);
    int col = j - 1;     col = col < 0 ? 0 : (col > 31 ? 31 : col);
    lds_sx[idx] = xs[c * LPIX + hh * 32 + col];
  }
  __syncthreads();

  // ---- A-fragment base pointers (one per (ci-half, co-tile)); all 9 taps
  // are imm offsets tap*128B from these. Data = W[co_l][ci0+kq*8 .. +8].
  const unsigned short* ap[2][2];
  #pragma unroll
  for (int ch = 0; ch < 2; ++ch)
    #pragma unroll
    for (int ct = 0; ct < 2; ++ct)
      ap[ch][ct] = wmfg + (size_t)(coh * 64 + cq * 32 + ct * 16 + n16) * 576
                   + ch * 32 + kq * 8;

  f32x4 acc[2][2] = {};

  #pragma unroll
  for (int tap = 0; tap < 9; ++tap) {
    const int dr = tap / 3, dc = tap % 3;
    const int rowst = rsel + dr;                 // staged row 0..3
    #pragma unroll
    for (int ch = 0; ch < 2; ++ch) {             // ci halves (0: ci<32, 1: ci>=32)
      const int g = (ch << 2) + kq;              // ci group 0..7
      bf16x8 bfr[2];
      #pragma unroll
      for (int t = 0; t < 2; ++t) {
        const int slot = t * 16 + n16 + dc;      // 0..33
        const int gs = (g ^ (slot & 7)) << 3;
        bfr[t] = *(const bf16x8*)(ldsB + ((rowst * 36 + slot) << 6) + gs);
      }
      #pragma unroll
      for (int ct = 0; ct < 2; ++ct) {
        bf16x8 a = *(const bf16x8*)(ap[ch][ct] + tap * 64);
        acc[0][ct] = __builtin_amdgcn_mfma_f32_16x16x32_bf16(a, bfr[0], acc[0][ct], 0, 0, 0);
        acc[1][ct] = __builtin_amdgcn_mfma_f32_16x16x32_bf16(a, bfr[1], acc[1][ct], 0, 0, 0);
      }
    }
  }
  __syncthreads();   // all waves done reading ldsB before lds_c overwrites it

  // ---- transpose acc through LDS: [px 0..63][co_l 0..63], XOR-swizzled f32x4
  // C layout (validated r5-r7): col(px in tile)=n16, row(co in tile)=kq*4+reg
  #pragma unroll
  for (int pt = 0; pt < 2; ++pt) {
    const int pxl = rsel * 32 + pt * 16 + n16;
    #pragma unroll
    for (int ct = 0; ct < 2; ++ct) {
      const int cog = cq * 8 + ct * 4 + kq;       // co_l/4 group: 0..15
      const int sg  = cog ^ (pxl & 7);
      *(f32x4*)&lds_c[pxl * 64 + sg * 4] = acc[pt][ct];
    }
  }
  __syncthreads();

  // ---- epilogue: wave wS -> co chunk [wS*16, wS*16+16) of this half; lane = px
  const int wS   = __builtin_amdgcn_readfirstlane(w);
  const int co0g = coh * 64 + wS * 16;
  const int pxl  = lane;

  float cvals[16];
  #pragma unroll
  for (int g = 0; g < 4; ++g) {
    const int cog = wS * 4 + g;
    const int sg  = cog ^ (pxl & 7);
    *(f32x4*)&cvals[g * 4] = *(const f32x4*)&lds_c[pxl * 64 + sg * 4];
  }

  // shape windows into registers (center-relative for channels 0,1)
  const int xbase = (pxl >> 5) * 36 + (pxl & 31);
  float swv[45];
  {
    const float c0 = lds_sx[0 * 144 + 37 + xbase];
    const float c1 = lds_sx[1 * 144 + 37 + xbase];
    #pragma unroll
    for (int c = 0; c < 5; ++c) {
      float ctr = (c == 0) ? c0 : ((c == 1) ? c1 : 0.f);
      #pragma unroll
      for (int s = 0; s < 3; ++s)
        #pragma unroll
        for (int dc = 0; dc < 3; ++dc)
          swv[c * 9 + s * 3 + dc] = lds_sx[c * 144 + s * 36 + dc + xbase] - ctr;
    }
  }

  // sd via wave-uniform scalar loads + pure VALU
  float sd[16];
  #pragma unroll
  for (int k = 0; k < 16; ++k) sd[k] = 0.f;
  const float* skt = sktg + co0g;
  #pragma unroll
  for (int j = 0; j < 45; ++j) {
    const float sv = swv[j];
    #pragma unroll
    for (int k = 0; k < 16; ++k)
      sd[k] += fabsf(sv - skt[j * 128 + k]);
  }

  // bias + saf = relu(conv/(sd+1)) + store + q partial
  float qpv = 0.f;
  float* ob = outg + ((size_t)b * 133 + co0g) * LPIX + (r0 + (pxl >> 5)) * 32 + (pxl & 31);
  #pragma unroll
  for (int k = 0; k < 16; ++k) {
    float v = (cvals[k] + cbg[co0g + k]) * __builtin_amdgcn_rcpf(sd[k] + 1.0f);
    v = v > 0.f ? v : 0.f;
    ob[(size_t)k * LPIX] = v;
    qpv = fmaf(v, w2g[co0g + k], qpv);
  }

  // in-block q reduction over the 4 waves (this half's 64 co)
  qred[w][lane] = qpv;
  __syncthreads();
  if (tid < 64) {
    float q = qred[0][tid] + qred[1][tid] + qred[2][tid] + qred[3][tid];
    qp[coh * 16384 + b * LPIX + r0 * 32 + tid] = q;
  }
}

// ---------------------------------------------------------------------------
// statsB: combine q halves, 3x3 zero-padded softmax + weighted window stats
// ---------------------------------------------------------------------------
__launch_bounds__(64)
__global__ void statsB(const float* __restrict__ xg,
                       const float* __restrict__ qp,
                       const float* __restrict__ b2g,
                       float* __restrict__ outg) {
  const int gid = blockIdx.x * 64 + threadIdx.x;  // 0..16383
  const int b = gid >> 10;
  const int h = (gid >> 5) & 31;
  const int w = gid & 31;

  const float b2 = b2g[0];
  const float* q0 = qp + (size_t)b * LPIX;
  float qv[9];
  float m = -1e30f;
  #pragma unroll
  for (int t = 0; t < 9; ++t) {
    int hh = h + t / 3 - 1, wc = w + t % 3 - 1;
    float v = 0.f;  // zero padding participates in softmax
    if ((unsigned)hh < 32u && (unsigned)wc < 32u) {
      int off = hh * 32 + wc;
      v = (q0[off] + q0[16384 + off] + b2) * 0.08838834764831845f;  // 1/sqrt(128)
    }
    qv[t] = v;
    m = fmaxf(m, v);
  }
  float ssum = 0.f;
  #pragma unroll
  for (int t = 0; t < 9; ++t) { qv[t] = expf(qv[t] - m); ssum += qv[t]; }
  const float inv = 1.f / ssum;

  const float* xs = xg + ((size_t)b * CX + CI) * LPIX;
  float um0[9], um1[9];
  float m0 = 0.f, m1 = 0.f, v1a = 0.f, v1b = 0.f, c1 = 0.f;
  #pragma unroll
  for (int t = 0; t < 9; ++t) {
    int hh = h + t / 3 - 1; hh = hh < 0 ? 0 : (hh > 31 ? 31 : hh);  // edge pad
    int wc = w + t % 3 - 1; wc = wc < 0 ? 0 : (wc > 31 ? 31 : wc);
    int off = hh * 32 + wc;
    float quv = qv[t] * inv;
    qv[t] = quv;
    float a0 = xs[off];
    float a1 = xs[LPIX + off];
    float b0 = xs[2 * LPIX + off];
    float b1 = xs[3 * LPIX + off];
    float cc = xs[4 * LPIX + off];
    um0[t] = a0; um1[t] = a1;
    m0 = fmaf(a0, quv, m0);
    m1 = fmaf(a1, quv, m1);
    v1a = fmaf(b0, quv, v1a);
    v1b = fmaf(b1, quv, v1b);
    c1 = fmaf(cc, quv, c1);
  }
  float var0 = v1a, var1 = v1b, cov = c1;
  #pragma unroll
  for (int t = 0; t < 9; ++t) {
    float d0 = um0[t] - m0, d1 = um1[t] - m1;
    var0 = fmaf(d0 * d0, qv[t], var0);
    var1 = fmaf(d1 * d1, qv[t], var1);
    cov  = fmaf(d0 * d1, qv[t], cov);
  }
  float* ob = outg + ((size_t)b * 133 + 128) * LPIX + h * 32 + w;
  ob[0 * LPIX] = m0;
  ob[1 * LPIX] = m1;
  ob[2 * LPIX] = var0;
  ob[3 * LPIX] = var1;
  ob[4 * LPIX] = cov;
}

extern "C" void kernel_launch(void* const* d_in, const int* in_sizes, int n_in,
                              void* d_out, int out_size, void* d_ws, size_t ws_size,
                              hipStream_t stream) {
  const float* x  = (const float*)d_in[0];
  const float* cw = (const float*)d_in[1];
  const float* cb = (const float*)d_in[2];
  const float* w2 = (const float*)d_in[3];
  const float* b2 = (const float*)d_in[4];
  const float* sk = (const float*)d_in[5];
  float* out = (float*)d_out;

  unsigned short* wmf = (unsigned short*)((char*)d_ws + WMF_OFF);
  float* skt = (float*)((char*)d_ws + SKT_OFF);
  float* qp  = (float*)((char*)d_ws + QP_OFF);

  prepW<<<dim3(311), dim3(256), 0, stream>>>(cw, sk, wmf, skt);
  convFused<<<dim3(512), dim3(256), 0, stream>>>(x, wmf, cb, w2, skt, qp, out);
  statsB<<<dim3(256), dim3(64), 0, stream>>>(x, qp, b2, out);
}

// Round 10
// 32.420 us; speedup vs baseline: 1.5546x; 1.1397x over previous
//
#include <hip/hip_runtime.h>
#include <math.h>

#define CI 64
#define CO 128
#define CX 69
#define LPIX 1024   // 32*32

typedef __attribute__((ext_vector_type(8))) short bf16x8;
typedef __attribute__((ext_vector_type(4))) float f32x4;

// ws byte offsets
#define WMF_OFF  0                        // u16[128][9][64] = 147456 B
#define SKT_OFF  147456                   // f32[45*128]     = 23040 B
#define QP_OFF   (147456 + 23040)         // f32[2*16*1024]  = 131072 B

__device__ __forceinline__ unsigned short f2bf(float f) {
  unsigned u = __float_as_uint(f);
  unsigned r = (u + 0x7fffu + ((u >> 16) & 1u)) >> 16;
  return (unsigned short)r;
}

// ---------------------------------------------------------------------------
// prepW: weights -> wmf[co][tap][ci] bf16 (a lane's 9-tap A-fragment set is
// one base pointer + tap*128B/ch*64B immediate offsets; layout validated r9);
// shapes_kernel -> skt[j][co] f32.
// ---------------------------------------------------------------------------
__launch_bounds__(256)
__global__ void prepW(const float* __restrict__ cwg,
                      const float* __restrict__ skg,
                      unsigned short* __restrict__ wmf,
                      float* __restrict__ skt) {
  int i = blockIdx.x * 256 + threadIdx.x;
  if (i < 128 * 9 * 64) {
    int co = i / 576, rem = i - co * 576;
    int tap = rem >> 6, ci = rem & 63;
    wmf[i] = f2bf(cwg[co * 576 + ci * 9 + tap]);
  } else {
    int d = i - 128 * 9 * 64;
    if (d < 45 * 128) {
      int j = d >> 7, co = d & 127;
      skt[j * 128 + co] = skg[co * 45 + j];
    }
  }
}

// ---------------------------------------------------------------------------
// convFused: conv3x3 (zero-pad) via bf16 MFMA 16x16x32 + fused epilogue.
// grid 512 = 16 b x 16 row-pairs x 2 co-halves; 512 thr = 8 waves.
// Wave = (row within pair, co-16-tile): A (9 taps x 2 ci-halves) pre-loaded
// into 18 b128 REGISTERS upfront (one latency exposure, no A-LDS, zero
// in-loop barriers). B staged in LDS (r7-validated swizzled image) via 4
// dwordx4 loads/thread. 23 KB LDS + <=128 VGPR -> 2 blocks/CU = 16 waves/CU.
// Epilogue: acc transposed through LDS (aliases dead ldsB), wave = 8-co
// chunk, lane = pixel: sd via wave-uniform s_loads + pure VALU.
// ---------------------------------------------------------------------------
__launch_bounds__(512, 4)
__global__ void convFused(const float* __restrict__ xg,
                          const unsigned short* __restrict__ wmfg,
                          const float* __restrict__ cbg,
                          const float* __restrict__ w2g,
                          const float* __restrict__ sktg,
                          float* __restrict__ qp,
                          float* __restrict__ outg) {
  __shared__ char arena[18432];       // ldsB (18432 B) -> lds_c (16384 B)
  __shared__ float lds_sx[5 * 144];   // shape rows, edge-clamped
  __shared__ float qred[8][64];

  unsigned short* ldsB = (unsigned short*)arena;
  float* lds_c = (float*)arena;

  const int tid = threadIdx.x;
  const int blk = blockIdx.x;
  const int coh = blk & 1;
  const int rp  = (blk >> 1) & 15;
  const int b   = blk >> 5;
  const int r0  = rp * 2;

  const int w    = tid >> 6;
  const int lane = tid & 63;
  const int rsel = w >> 2;          // MFMA-phase: wave's row within pair
  const int ct   = w & 3;           // MFMA-phase: co-16-tile within half
  const int n16  = lane & 15;
  const int kq   = lane >> 4;

  const float* xb = xg + (size_t)b * CX * LPIX;
  const float* xs = xb + CI * LPIX;

  // ---- A fragments into registers: 9 taps x 2 ci-halves, one b128 each.
  // Data = W[co_g][tap][ch*32 + kq*8 .. +8]  (r9-validated layout & frag).
  bf16x8 areg[2][9];
  {
    const unsigned short* abase =
        wmfg + (size_t)(coh * 64 + ct * 16 + n16) * 576 + kq * 8;
    #pragma unroll
    for (int ch = 0; ch < 2; ++ch)
      #pragma unroll
      for (int tap = 0; tap < 9; ++tap)
        areg[ch][tap] = *(const bf16x8*)(abase + tap * 64 + ch * 32);
  }

  // ---- stage B: x rows r0-1..r0+2, col slot s holds global col s-1, bf16,
  // ci-group XOR-swizzled by (slot&7). Zero rows/cols OOB. 4 dwordx4/thread.
  {
    const int row  = tid >> 7;         // 0..3
    const int cip  = (tid >> 2) & 31;  // ci pair
    const int colq = tid & 3;          // 8-col group
    const int ci   = cip * 2;
    const int c0   = colq * 8;
    const int grow = r0 - 1 + row;
    f32x4 u0a = {}, u0b = {}, u1a = {}, u1b = {};
    if ((unsigned)grow < 32u) {
      const float* p0 = xb + ci * LPIX + grow * 32 + c0;
      u0a = *(const f32x4*)p0;          u0b = *(const f32x4*)(p0 + 4);
      u1a = *(const f32x4*)(p0 + LPIX); u1b = *(const f32x4*)(p0 + LPIX + 4);
    }
    #pragma unroll
    for (int cc = 0; cc < 8; ++cc) {
      float f0 = (cc < 4) ? u0a[cc] : u0b[cc - 4];
      float f1 = (cc < 4) ? u1a[cc] : u1b[cc - 4];
      unsigned v = (unsigned)f2bf(f0) | ((unsigned)f2bf(f1) << 16);
      const int slot  = c0 + cc + 1;   // 1..32
      const int gslot = ((ci >> 3) << 3) ^ ((slot & 7) << 3);
      ((unsigned*)ldsB)[(((row * 36 + slot) << 6) + gslot + (ci & 7)) >> 1] = v;
    }
    // zero pad slots 0,33,34,35 (4 rows x 32 ci-pairs each = 512 u32)
    {
      const int prw = tid >> 7;
      const int s4  = (tid >> 5) & 3;
      const int sl  = (s4 == 0) ? 0 : (32 + s4);
      const int ci2 = (tid & 31) * 2;
      const int gsl = ((ci2 >> 3) << 3) ^ ((sl & 7) << 3);
      ((unsigned*)ldsB)[(((prw * 36 + sl) << 6) + gsl + (ci2 & 7)) >> 1] = 0;
    }
  }

  // ---- stage shape rows (edge clamp) for the epilogue
  for (int idx = tid; idx < 5 * 144; idx += 512) {
    int c = idx / 144, rem = idx - c * 144;
    int s = rem / 36, j = rem - s * 36;
    int hh = r0 - 1 + s; hh = hh < 0 ? 0 : (hh > 31 ? 31 : hh);
    int col = j - 1;     col = col < 0 ? 0 : (col > 31 ? 31 : col);
    lds_sx[idx] = xs[c * LPIX + hh * 32 + col];
  }
  __syncthreads();

  // ---- barrier-free tap loop: per tap 4 ds_read_b128 + 4 MFMA (A in regs)
  f32x4 acc[2] = {};
  #pragma unroll
  for (int tap = 0; tap < 9; ++tap) {
    const int dr = tap / 3, dc = tap % 3;
    const int rowst = rsel + dr;                 // staged row 0..3
    #pragma unroll
    for (int ch = 0; ch < 2; ++ch) {             // ci halves
      const int g = (ch << 2) + kq;              // ci group 0..7
      #pragma unroll
      for (int pt = 0; pt < 2; ++pt) {
        const int slot = pt * 16 + n16 + dc;     // 0..33
        const int gs = (g ^ (slot & 7)) << 3;
        bf16x8 bfr = *(const bf16x8*)(ldsB + ((rowst * 36 + slot) << 6) + gs);
        acc[pt] = __builtin_amdgcn_mfma_f32_16x16x32_bf16(areg[ch][tap], bfr,
                                                          acc[pt], 0, 0, 0);
      }
    }
  }
  __syncthreads();   // all waves done reading ldsB before lds_c overwrites it

  // ---- transpose acc through LDS: [px 0..63][co_l 0..63], XOR-swizzled f32x4
  // C layout (validated r5-r7): col(px in tile)=n16, row(co in tile)=kq*4+reg
  #pragma unroll
  for (int pt = 0; pt < 2; ++pt) {
    const int pxl = rsel * 32 + pt * 16 + n16;
    const int cog = ct * 4 + kq;                 // co_l/4 group: 0..15
    const int sg  = cog ^ (pxl & 7);
    *(f32x4*)&lds_c[pxl * 64 + sg * 4] = acc[pt];
  }
  __syncthreads();

  // ---- epilogue: wave wS -> co chunk [wS*8, wS*8+8) of this half; lane = px
  const int wS   = __builtin_amdgcn_readfirstlane(w);
  const int co0g = coh * 64 + wS * 8;
  const int pxl  = lane;

  float cvals[8];
  #pragma unroll
  for (int g = 0; g < 2; ++g) {
    const int cog = wS * 2 + g;
    const int sg  = cog ^ (pxl & 7);
    *(f32x4*)&cvals[g * 4] = *(const f32x4*)&lds_c[pxl * 64 + sg * 4];
  }

  // shape windows into registers (center-relative for channels 0,1)
  const int xbase = (pxl >> 5) * 36 + (pxl & 31);
  float swv[45];
  {
    const float c0 = lds_sx[0 * 144 + 37 + xbase];
    const float c1 = lds_sx[1 * 144 + 37 + xbase];
    #pragma unroll
    for (int c = 0; c < 5; ++c) {
      float ctr = (c == 0) ? c0 : ((c == 1) ? c1 : 0.f);
      #pragma unroll
      for (int s = 0; s < 3; ++s)
        #pragma unroll
        for (int dc = 0; dc < 3; ++dc)
          swv[c * 9 + s * 3 + dc] = lds_sx[c * 144 + s * 36 + dc + xbase] - ctr;
    }
  }

  // sd via wave-uniform scalar loads + pure VALU (8 co per thread)
  float sd[8];
  #pragma unroll
  for (int k = 0; k < 8; ++k) sd[k] = 0.f;
  const float* skt = sktg + co0g;
  #pragma unroll
  for (int j = 0; j < 45; ++j) {
    const float sv = swv[j];
    #pragma unroll
    for (int k = 0; k < 8; ++k)
      sd[k] += fabsf(sv - skt[j * 128 + k]);
  }

  // bias + saf = relu(conv/(sd+1)) + store + q partial
  float qpv = 0.f;
  float* ob = outg + ((size_t)b * 133 + co0g) * LPIX + (r0 + (pxl >> 5)) * 32 + (pxl & 31);
  #pragma unroll
  for (int k = 0; k < 8; ++k) {
    float v = (cvals[k] + cbg[co0g + k]) * __builtin_amdgcn_rcpf(sd[k] + 1.0f);
    v = v > 0.f ? v : 0.f;
    ob[(size_t)k * LPIX] = v;
    qpv = fmaf(v, w2g[co0g + k], qpv);
  }

  // in-block q reduction over the 8 waves (this half's 64 co)
  qred[w][lane] = qpv;
  __syncthreads();
  if (tid < 64) {
    float q = 0.f;
    #pragma unroll
    for (int w8 = 0; w8 < 8; ++w8) q += qred[w8][tid];
    qp[coh * 16384 + b * LPIX + r0 * 32 + tid] = q;
  }
}

// ---------------------------------------------------------------------------
// statsB: combine q halves, 3x3 zero-padded softmax + weighted window stats
// ---------------------------------------------------------------------------
__launch_bounds__(64)
__global__ void statsB(const float* __restrict__ xg,
                       const float* __restrict__ qp,
                       const float* __restrict__ b2g,
                       float* __restrict__ outg) {
  const int gid = blockIdx.x * 64 + threadIdx.x;  // 0..16383
  const int b = gid >> 10;
  const int h = (gid >> 5) & 31;
  const int w = gid & 31;

  const float b2 = b2g[0];
  const float* q0 = qp + (size_t)b * LPIX;
  float qv[9];
  float m = -1e30f;
  #pragma unroll
  for (int t = 0; t < 9; ++t) {
    int hh = h + t / 3 - 1, wc = w + t % 3 - 1;
    float v = 0.f;  // zero padding participates in softmax
    if ((unsigned)hh < 32u && (unsigned)wc < 32u) {
      int off = hh * 32 + wc;
      v = (q0[off] + q0[16384 + off] + b2) * 0.08838834764831845f;  // 1/sqrt(128)
    }
    qv[t] = v;
    m = fmaxf(m, v);
  }
  float ssum = 0.f;
  #pragma unroll
  for (int t = 0; t < 9; ++t) { qv[t] = expf(qv[t] - m); ssum += qv[t]; }
  const float inv = 1.f / ssum;

  const float* xs = xg + ((size_t)b * CX + CI) * LPIX;
  float um0[9], um1[9];
  float m0 = 0.f, m1 = 0.f, v1a = 0.f, v1b = 0.f, c1 = 0.f;
  #pragma unroll
  for (int t = 0; t < 9; ++t) {
    int hh = h + t / 3 - 1; hh = hh < 0 ? 0 : (hh > 31 ? 31 : hh);  // edge pad
    int wc = w + t % 3 - 1; wc = wc < 0 ? 0 : (wc > 31 ? 31 : wc);
    int off = hh * 32 + wc;
    float quv = qv[t] * inv;
    qv[t] = quv;
    float a0 = xs[off];
    float a1 = xs[LPIX + off];
    float b0 = xs[2 * LPIX + off];
    float b1 = xs[3 * LPIX + off];
    float cc = xs[4 * LPIX + off];
    um0[t] = a0; um1[t] = a1;
    m0 = fmaf(a0, quv, m0);
    m1 = fmaf(a1, quv, m1);
    v1a = fmaf(b0, quv, v1a);
    v1b = fmaf(b1, quv, v1b);
    c1 = fmaf(cc, quv, c1);
  }
  float var0 = v1a, var1 = v1b, cov = c1;
  #pragma unroll
  for (int t = 0; t < 9; ++t) {
    float d0 = um0[t] - m0, d1 = um1[t] - m1;
    var0 = fmaf(d0 * d0, qv[t], var0);
    var1 = fmaf(d1 * d1, qv[t], var1);
    cov  = fmaf(d0 * d1, qv[t], cov);
  }
  float* ob = outg + ((size_t)b * 133 + 128) * LPIX + h * 32 + w;
  ob[0 * LPIX] = m0;
  ob[1 * LPIX] = m1;
  ob[2 * LPIX] = var0;
  ob[3 * LPIX] = var1;
  ob[4 * LPIX] = cov;
}

extern "C" void kernel_launch(void* const* d_in, const int* in_sizes, int n_in,
                              void* d_out, int out_size, void* d_ws, size_t ws_size,
                              hipStream_t stream) {
  const float* x  = (const float*)d_in[0];
  const float* cw = (const float*)d_in[1];
  const float* cb = (const float*)d_in[2];
  const float* w2 = (const float*)d_in[3];
  const float* b2 = (const float*)d_in[4];
  const float* sk = (const float*)d_in[5];
  float* out = (float*)d_out;

  unsigned short* wmf = (unsigned short*)((char*)d_ws + WMF_OFF);
  float* skt = (float*)((char*)d_ws + SKT_OFF);
  float* qp  = (float*)((char*)d_ws + QP_OFF);

  prepW<<<dim3(311), dim3(256), 0, stream>>>(cw, sk, wmf, skt);
  convFused<<<dim3(512), dim3(512), 0, stream>>>(x, wmf, cb, w2, skt, qp, out);
  statsB<<<dim3(256), dim3(64), 0, stream>>>(x, qp, b2, out);
}